// Round 8
// baseline (137.893 us; speedup 1.0000x reference)
//
#include <hip/hip_runtime.h>
#include <hip/hip_bf16.h>

typedef unsigned int u32;
typedef unsigned short u16;
typedef float f32x4 __attribute__((ext_vector_type(4)));
typedef short s16x8 __attribute__((ext_vector_type(8)));

#define B_   2
#define S_   2048
#define HID_ 512
#define H_   8
#define HKV_ 2
#define QB_  8
#define VB_  16
#define NQ_  64
#define HVB_ 128
#define MFIX_  17.0f

__device__ __forceinline__ u16 f2bf(float f) {
    u32 b = __builtin_bit_cast(u32, f);
    b += 0x7FFFu + ((b >> 16) & 1u);
    return (u16)(b >> 16);
}
__device__ __forceinline__ float bf2f(u16 h) {
    u32 b = ((u32)h) << 16;
    return __builtin_bit_cast(float, b);
}
__device__ __forceinline__ f32x4 mfma16(s16x8 a, s16x8 b, f32x4 c) {
    return __builtin_amdgcn_mfma_f32_16x16x32_bf16(a, b, c, 0, 0, 0);
}
// NaN-free by range analysis: e in [0,inf] -> rcp in [0,1] -> result in [-1,1].
__device__ __forceinline__ float fast_tanh(float x) {
    float e = __expf(2.f * x);
    return 1.f - 2.f * __builtin_amdgcn_rcpf(e + 1.f);
}
__device__ __forceinline__ float fast_sigmoid(float x) {
    return __builtin_amdgcn_rcpf(1.f + __expf(-x));
}

// ------------------------------------------------- K0: weights -> single bf16 planes
// Wc [128][512] row-major (rows 112..127 zero-padded); Wob [512][128] row-major.
__global__ void k0_convert(const float* __restrict__ Wq, const float* __restrict__ Wk,
                           const float* __restrict__ Wv, const float* __restrict__ Wo,
                           u16* __restrict__ Wc, u16* __restrict__ Wob) {
    int idx = blockIdx.x * 256 + threadIdx.x;          // grid 256 -> 65536 threads
    {
        int n = idx >> 9, k = idx & 511;
        float v = (n < NQ_) ? Wq[n * HID_ + k]
                : (n < NQ_ + 16) ? Wk[(n - NQ_) * HID_ + k]
                : (n < 112) ? Wv[(n - NQ_ - 16) * HID_ + k] : 0.f;
        Wc[idx] = f2bf(v);                             // idx == n*512 + k
    }
    Wob[idx] = f2bf(Wo[idx]);                          // 512*128 == 65536
}

// ------------------------------------------------- K1: projections (single bf16, no LDS)
// grid 256 (16 rows), block 256 (4 waves); wave wv owns n-frags {wv, wv+4}.
// q is PRE-SCALED by 2^-4 (exact exponent shift) so k2's scores need no scale mul.
__global__ __launch_bounds__(256) void k1_proj(
    const float* __restrict__ hidden, const u16* __restrict__ Wc,
    u16* __restrict__ qb, u16* __restrict__ kb, u16* __restrict__ vt)
{
    const int tid = threadIdx.x;
    const int r0 = blockIdx.x * 16;
    const int wv = tid >> 6, lane = tid & 63;
    const int li = lane & 15, lo4 = lane >> 4;

    const float* hrow = hidden + (r0 + li) * HID_;

    f32x4 acc[2];
    acc[0] = (f32x4){0.f, 0.f, 0.f, 0.f};
    acc[1] = (f32x4){0.f, 0.f, 0.f, 0.f};

    #pragma unroll
    for (int kc = 0; kc < 16; ++kc) {
        f32x4 x0 = *(const f32x4*)&hrow[32 * kc + 8 * lo4];
        f32x4 x1 = *(const f32x4*)&hrow[32 * kc + 8 * lo4 + 4];
        s16x8 a = { (short)f2bf(x0[0]), (short)f2bf(x0[1]), (short)f2bf(x0[2]), (short)f2bf(x0[3]),
                    (short)f2bf(x1[0]), (short)f2bf(x1[1]), (short)f2bf(x1[2]), (short)f2bf(x1[3]) };
        #pragma unroll
        for (int u = 0; u < 2; ++u) {
            int n = (wv + 4 * u) * 16 + li;
            s16x8 bfr = *(const s16x8*)&Wc[n * HID_ + 32 * kc + 8 * lo4];
            acc[u] = mfma16(a, bfr, acc[u]);
        }
    }

    #pragma unroll
    for (int u = 0; u < 2; ++u) {
        int n = (wv + 4 * u) * 16 + li;
        if (n < 112) {
            #pragma unroll
            for (int reg = 0; reg < 4; ++reg) {
                int gs = r0 + 4 * lo4 + reg;
                int b = gs >> 11, s = gs & 2047;
                float pre = acc[u][reg];
                if (n < NQ_) {
                    int h = n >> 3, bit = n & 7;
                    qb[(((b * H_ + h) * S_) + s) * QB_ + bit] = f2bf(fast_tanh(pre) * 0.0625f);
                } else if (n < NQ_ + 16) {
                    int nk = n - NQ_;
                    kb[(((b * HKV_ + (nk >> 3)) * S_) + s) * QB_ + (nk & 7)] = f2bf(fast_tanh(pre));
                } else {
                    int nv = n - NQ_ - 16;
                    int hv = nv >> 4, vb = nv & 15;
                    u16 sig = f2bf(fast_sigmoid(pre));
                    if (s > 0)
                        vt[((b * HKV_ + hv) * VB_ + vb) * S_ + (s - 1)] = sig;   // suffix shift
                    if (s == S_ - 1)
                        vt[((b * HKV_ + hv) * VB_ + vb) * S_ + (S_ - 1)] = 0;
                }
            }
        }
    }
}

// ------------------------------------------------- K2: fused windowed attention
// grid 1024 = 64 row-blocks(32 i) x 16 bh; block 256 = 4 waves = 4 J-groups.
// Each wave owns ALL 32 i-rows and a strided subset of J-tiles. K/Q/V direct
// from global (L1/L2-resident), P via per-wave LDS (same-wave ordering, no
// barrier). ZERO __syncthreads in the main loop; one merge barrier at the end.
__global__ __launch_bounds__(256, 4) void k2_attn(
    const u16* __restrict__ qb, const u16* __restrict__ kb, const u16* __restrict__ vt,
    const float* __restrict__ vemb0, const float* __restrict__ vemb1,
    u16* __restrict__ AO)
{
    __shared__ __align__(16) u16 psa[4][32 * 72];      // per-wave P scratch
    __shared__ float Om[4][2][16][16];                 // [group][ig][row][li]
    __shared__ float lv[4][2][16];

    const int bid = blockIdx.x;
    const int rb = bid >> 4;
    const int r  = (rb < 32) ? (63 - rb) : (rb - 32);  // heavy-first complementary pairing
    const int I0 = r * 32;
    const int nJ = ((I0 + 30) >> 6) + 1;               // j <= I0+30 needed
    const int bh = bid & 15;
    const int b = bh >> 3, h = bh & 7, hkv = h >> 2;

    const int g = threadIdx.x >> 6;                    // wave = J-group 0..3
    const int lane = threadIdx.x & 63;
    const int li = lane & 15, lo4 = lane >> 4;

    u16* psw = psa[g];
    const u16* kpl = kb + ((b * HKV_ + hkv) * S_) * QB_ + (li + lo4 - 31) * QB_;
    const u16* vtp = vt + ((b * HKV_ + hkv) * VB_) * S_ + li * S_ + 8 * lo4;

    // hoist Q A-frags for both 16-row sub-tiles (rows < 0 zeroed; only I0==0 triggers)
    s16x8 qf[2][8];
    #pragma unroll
    for (int ig = 0; ig < 2; ++ig) {
        const int gr0 = I0 + 16 * ig + li - 31 + lo4;
        const u16* qp = qb + ((b * H_ + h) * S_) * QB_ + gr0 * QB_;
        #pragma unroll
        for (int kk = 0; kk < 8; ++kk) {
            s16x8 v = {0, 0, 0, 0, 0, 0, 0, 0};
            if (gr0 + 4 * kk >= 0) v = *(const s16x8*)(qp + kk * 32);
            qf[ig][kk] = v;
        }
    }

    // per-owned-row constants: i, 1/(i+1), 16/(i+1)
    int ibase[2];
    float binv[2][4], bstep[2][4];
    #pragma unroll
    for (int ig = 0; ig < 2; ++ig) {
        ibase[ig] = I0 + 16 * ig + 4 * lo4;
        #pragma unroll
        for (int reg = 0; reg < 4; ++reg) {
            float d = (float)(ibase[ig] + reg + 1);
            float rc = __builtin_amdgcn_rcpf(d);
            rc = rc * (2.f - d * rc);                  // NR: f32-exact for our range
            binv[ig][reg] = rc;
            bstep[ig][reg] = 16.f * rc;
        }
    }

    f32x4 O[2];
    O[0] = (f32x4){0.f, 0.f, 0.f, 0.f};
    O[1] = (f32x4){0.f, 0.f, 0.f, 0.f};
    float lsum[2][4] = {{0.f, 0.f, 0.f, 0.f}, {0.f, 0.f, 0.f, 0.f}};

    for (int jt = g; jt < nJ; jt += 4) {
        const int J0 = jt * 64;

        // ---- V frags (global, one b128 per K=32 slab)
        s16x8 vfr0 = *(const s16x8*)(vtp + J0);
        s16x8 vfr1 = *(const s16x8*)(vtp + J0 + 32);

        // ---- K frags: 20 dedup'd b128 global loads; frag(ns,kk) = ld[4ns+kk]
        s16x8 ld[20];
        const u16* kt = kpl + jt * 512;
        if (jt == 0) {
            #pragma unroll
            for (int m = 0; m < 20; ++m) {
                s16x8 v = {0, 0, 0, 0, 0, 0, 0, 0};
                if (li + lo4 + 4 * m >= 31) v = *(const s16x8*)(kt + 32 * m);
                ld[m] = v;
            }
        } else {
            #pragma unroll
            for (int m = 0; m < 20; ++m)
                ld[m] = *(const s16x8*)(kt + 32 * m);
        }

        // ---- QK^T (implicit window-unfold, K=256): 64 MFMAs
        f32x4 sacc[2][4];
        #pragma unroll
        for (int ig = 0; ig < 2; ++ig)
            #pragma unroll
            for (int ns = 0; ns < 4; ++ns)
                sacc[ig][ns] = (f32x4){0.f, 0.f, 0.f, 0.f};
        #pragma unroll
        for (int m = 0; m < 20; ++m) {
            s16x8 f = ld[m];
            {
                int kk = m & 3, ns = m >> 2;
                if (ns < 4) {
                    sacc[0][ns] = mfma16(qf[0][kk], f, sacc[0][ns]);
                    sacc[1][ns] = mfma16(qf[1][kk], f, sacc[1][ns]);
                }
            }
            {
                int kk = (m & 3) + 4, ns = (m >> 2) - 1;
                if (ns >= 0) {
                    sacc[0][ns] = mfma16(qf[0][kk], f, sacc[0][ns]);
                    sacc[1][ns] = mfma16(qf[1][kk], f, sacc[1][ns]);
                }
            }
        }

        // ---- bias + strict mask + fixed-max exp (q pre-scaled); P -> per-wave LDS
        const float jlif = (float)(J0 + li);
        #pragma unroll
        for (int ig = 0; ig < 2; ++ig) {
            const bool edgev = (J0 + 63) >= (I0 + 16 * ig);   // wave-uniform
            #pragma unroll
            for (int reg = 0; reg < 4; ++reg) {
                float bns = fmaf(jlif, binv[ig][reg], -MFIX_);
                const int irow = ibase[ig] + reg;
                float p[4];
                #pragma unroll
                for (int ns = 0; ns < 4; ++ns) {
                    float e = __expf(sacc[ig][ns][reg] + bns);
                    if (edgev)
                        e = (J0 + 16 * ns + li < irow) ? e : 0.f;
                    p[ns] = e;
                    bns += bstep[ig][reg];
                }
                lsum[ig][reg] += (p[0] + p[1]) + (p[2] + p[3]);
                #pragma unroll
                for (int ns = 0; ns < 4; ++ns)
                    psw[(ig * 16 + 4 * lo4 + reg) * 72 + 16 * ns + li] = f2bf(p[ns]);
            }
        }

        // ---- PV: P from per-wave LDS (same-wave ordering), V from global
        #pragma unroll
        for (int ig = 0; ig < 2; ++ig) {
            s16x8 pa0 = *(const s16x8*)&psw[(ig * 16 + li) * 72 + 8 * lo4];
            s16x8 pa1 = *(const s16x8*)&psw[(ig * 16 + li) * 72 + 32 + 8 * lo4];
            O[ig] = mfma16(pa0, vfr0, O[ig]);
            O[ig] = mfma16(pa1, vfr1, O[ig]);
        }
    }

    // ---- publish partials (plain-sum merge: fixed max => no rescale)
    #pragma unroll
    for (int ig = 0; ig < 2; ++ig) {
        #pragma unroll
        for (int reg = 0; reg < 4; ++reg) {
            float l = lsum[ig][reg];
            l += __shfl_xor(l, 1);
            l += __shfl_xor(l, 2);
            l += __shfl_xor(l, 4);
            l += __shfl_xor(l, 8);
            Om[g][ig][4 * lo4 + reg][li] = O[ig][reg];
            if (li == 0) lv[g][ig][4 * lo4 + reg] = l;
        }
    }
    __syncthreads();

    if (g == 0) {
        const int hc = h * VB_ + li;
        const float e0 = vemb0[hc], e1 = vemb1[hc];
        #pragma unroll
        for (int ig = 0; ig < 2; ++ig) {
            #pragma unroll
            for (int reg = 0; reg < 4; ++reg) {
                const int row = 4 * lo4 + reg;
                float Oc = (Om[0][ig][row][li] + Om[1][ig][row][li])
                         + (Om[2][ig][row][li] + Om[3][ig][row][li]);
                float lc = (lv[0][ig][row] + lv[1][ig][row])
                         + (lv[2][ig][row] + lv[3][ig][row]);
                float lr = fmaxf(lc, 1e-30f);
                float rinv = __builtin_amdgcn_rcpf(lr);
                rinv = rinv * (2.f - lr * rinv);
                float o = Oc * rinv;
                const int s = I0 + 16 * ig + row;
                AO[(b * S_ + s) * HVB_ + hc] = f2bf(e0 + o * (e1 - e0));
            }
        }
    }
}

// ------------------------------------------------- K3: AO(bf16) @ Wo^T(bf16), no LDS
// grid 1024 = 256 row-tiles x 4 col-groups; block 256 (4 waves), wave owns 2 frags
__global__ __launch_bounds__(256) void k3_out(
    const u16* __restrict__ AO, const u16* __restrict__ Wob,
    float* __restrict__ out)
{
    const int tid = threadIdx.x;
    const int r0 = (blockIdx.x >> 2) * 16;
    const int cg = blockIdx.x & 3;
    const int wv = tid >> 6, lane = tid & 63;
    const int li = lane & 15, lo4 = lane >> 4;

    const u16* arow = AO + (r0 + li) * HVB_;

    f32x4 acc[2];
    acc[0] = (f32x4){0.f, 0.f, 0.f, 0.f};
    acc[1] = (f32x4){0.f, 0.f, 0.f, 0.f};

    #pragma unroll
    for (int kc = 0; kc < 4; ++kc) {
        s16x8 a = *(const s16x8*)&arow[32 * kc + 8 * lo4];
        #pragma unroll
        for (int u = 0; u < 2; ++u) {
            int o = cg * 128 + (wv + 4 * u) * 16 + li;
            s16x8 bfr = *(const s16x8*)&Wob[o * HVB_ + 32 * kc + 8 * lo4];
            acc[u] = mfma16(a, bfr, acc[u]);
        }
    }

    #pragma unroll
    for (int u = 0; u < 2; ++u) {
        int o = cg * 128 + (wv + 4 * u) * 16 + li;
        #pragma unroll
        for (int reg = 0; reg < 4; ++reg)
            out[(r0 + 4 * lo4 + reg) * HID_ + o] = acc[u][reg];
    }
}

// ------------------------------------------------- launch
extern "C" void kernel_launch(void* const* d_in, const int* in_sizes, int n_in,
                              void* d_out, int out_size, void* d_ws, size_t ws_size,
                              hipStream_t stream)
{
    (void)in_sizes; (void)n_in; (void)out_size;
    const float* hidden = (const float*)d_in[0];
    const float* Wq = (const float*)d_in[1];
    const float* Wk = (const float*)d_in[2];
    const float* Wv = (const float*)d_in[3];
    const float* Wo = (const float*)d_in[4];
    const float* ve0 = (const float*)d_in[5];
    const float* ve1 = (const float*)d_in[6];
    float* out = (float*)d_out;

    char* base = (char*)d_ws;
    u16* qb  = (u16*)(base);                        // [B,H,S,8]      524288 B (pre-scaled 2^-4)
    u16* kb  = (u16*)(base + 524288);               // [B,HKV,S,8]    131072 B
    u16* vt  = (u16*)(base + 655360);               // [B,HKV,16,S]   262144 B (shifted, transposed)
    u16* AO  = (u16*)(base + 917504);               // [B*S,128] bf16 1048576 B
    u16* Wc  = (u16*)(base + 1966080);              // [128,512] bf16  131072 B (padded)
    u16* Wob = (u16*)(base + 2097152);              // [512,128] bf16  131072 B -> end 2228224
    if (ws_size < 2228224) return;

    hipLaunchKernelGGL(k0_convert, dim3(256), dim3(256), 0, stream,
                       Wq, Wk, Wv, Wo, Wc, Wob);
    hipLaunchKernelGGL(k1_proj, dim3(256), dim3(256), 0, stream,
                       hidden, Wc, qb, kb, vt);
    hipLaunchKernelGGL(k2_attn, dim3(1024), dim3(256), 0, stream,
                       qb, kb, vt, ve0, ve1, AO);
    hipLaunchKernelGGL(k3_out, dim3(1024), dim3(256), 0, stream,
                       AO, Wob, out);
}

// Round 9
// 65.516 us; speedup vs baseline: 2.1047x; 2.1047x over previous
//
#include <hip/hip_runtime.h>
#include <hip/hip_bf16.h>

typedef unsigned int u32;
typedef unsigned short u16;
typedef float f32x4 __attribute__((ext_vector_type(4)));
typedef short s16x8 __attribute__((ext_vector_type(8)));

#define B_   2
#define S_   2048
#define HID_ 512
#define H_   8
#define HKV_ 2
#define QB_  8
#define VB_  16
#define NQ_  64
#define HVB_ 128
#define MFIX_  17.0f

__device__ __forceinline__ u16 f2bf(float f) {
    u32 b = __builtin_bit_cast(u32, f);
    b += 0x7FFFu + ((b >> 16) & 1u);
    return (u16)(b >> 16);
}
__device__ __forceinline__ float bf2f(u16 h) {
    u32 b = ((u32)h) << 16;
    return __builtin_bit_cast(float, b);
}
__device__ __forceinline__ f32x4 mfma16(s16x8 a, s16x8 b, f32x4 c) {
    return __builtin_amdgcn_mfma_f32_16x16x32_bf16(a, b, c, 0, 0, 0);
}
// NaN-free by range analysis: e in [0,inf] -> rcp in [0,1] -> result in [-1,1].
__device__ __forceinline__ float fast_tanh(float x) {
    float e = __expf(2.f * x);
    return 1.f - 2.f * __builtin_amdgcn_rcpf(e + 1.f);
}
__device__ __forceinline__ float fast_sigmoid(float x) {
    return __builtin_amdgcn_rcpf(1.f + __expf(-x));
}

// ------------------------------------------------- K0: weights -> single bf16 planes
// Wc [128][512] row-major (rows 112..127 zero-padded); Wob [512][128] row-major.
__global__ void k0_convert(const float* __restrict__ Wq, const float* __restrict__ Wk,
                           const float* __restrict__ Wv, const float* __restrict__ Wo,
                           u16* __restrict__ Wc, u16* __restrict__ Wob) {
    int idx = blockIdx.x * 256 + threadIdx.x;          // grid 256 -> 65536 threads
    {
        int n = idx >> 9, k = idx & 511;
        float v = (n < NQ_) ? Wq[n * HID_ + k]
                : (n < NQ_ + 16) ? Wk[(n - NQ_) * HID_ + k]
                : (n < 112) ? Wv[(n - NQ_ - 16) * HID_ + k] : 0.f;
        Wc[idx] = f2bf(v);                             // idx == n*512 + k
    }
    Wob[idx] = f2bf(Wo[idx]);                          // 512*128 == 65536
}

// ------------------------------------------------- K1: projections (single bf16, no LDS)
// grid 256 (16 rows), block 256 (4 waves); wave wv owns n-frags {wv, wv+4}.
// q is PRE-SCALED by 2^-4 (exact exponent shift) so k2's scores need no scale mul.
__global__ __launch_bounds__(256) void k1_proj(
    const float* __restrict__ hidden, const u16* __restrict__ Wc,
    u16* __restrict__ qb, u16* __restrict__ kb, u16* __restrict__ vt)
{
    const int tid = threadIdx.x;
    const int r0 = blockIdx.x * 16;
    const int wv = tid >> 6, lane = tid & 63;
    const int li = lane & 15, lo4 = lane >> 4;

    const float* hrow = hidden + (r0 + li) * HID_;

    f32x4 acc[2];
    acc[0] = (f32x4){0.f, 0.f, 0.f, 0.f};
    acc[1] = (f32x4){0.f, 0.f, 0.f, 0.f};

    #pragma unroll
    for (int kc = 0; kc < 16; ++kc) {
        f32x4 x0 = *(const f32x4*)&hrow[32 * kc + 8 * lo4];
        f32x4 x1 = *(const f32x4*)&hrow[32 * kc + 8 * lo4 + 4];
        s16x8 a = { (short)f2bf(x0[0]), (short)f2bf(x0[1]), (short)f2bf(x0[2]), (short)f2bf(x0[3]),
                    (short)f2bf(x1[0]), (short)f2bf(x1[1]), (short)f2bf(x1[2]), (short)f2bf(x1[3]) };
        #pragma unroll
        for (int u = 0; u < 2; ++u) {
            int n = (wv + 4 * u) * 16 + li;
            s16x8 bfr = *(const s16x8*)&Wc[n * HID_ + 32 * kc + 8 * lo4];
            acc[u] = mfma16(a, bfr, acc[u]);
        }
    }

    #pragma unroll
    for (int u = 0; u < 2; ++u) {
        int n = (wv + 4 * u) * 16 + li;
        if (n < 112) {
            #pragma unroll
            for (int reg = 0; reg < 4; ++reg) {
                int gs = r0 + 4 * lo4 + reg;
                int b = gs >> 11, s = gs & 2047;
                float pre = acc[u][reg];
                if (n < NQ_) {
                    int h = n >> 3, bit = n & 7;
                    qb[(((b * H_ + h) * S_) + s) * QB_ + bit] = f2bf(fast_tanh(pre) * 0.0625f);
                } else if (n < NQ_ + 16) {
                    int nk = n - NQ_;
                    kb[(((b * HKV_ + (nk >> 3)) * S_) + s) * QB_ + (nk & 7)] = f2bf(fast_tanh(pre));
                } else {
                    int nv = n - NQ_ - 16;
                    int hv = nv >> 4, vb = nv & 15;
                    u16 sig = f2bf(fast_sigmoid(pre));
                    if (s > 0)
                        vt[((b * HKV_ + hv) * VB_ + vb) * S_ + (s - 1)] = sig;   // suffix shift
                    if (s == S_ - 1)
                        vt[((b * HKV_ + hv) * VB_ + vb) * S_ + (S_ - 1)] = 0;
                }
            }
        }
    }
}

// ------------------------------------------------- K2: fused windowed attention
// grid 1024 = 64 row-blocks(32 i) x 16 bh; block 256 = 4 waves = 4 J-groups.
// Barrier-free main loop; K loads chunked 5x4 to bound register pressure
// (r8 lesson: launch_bounds(256,4) + flat ld[20] -> 128-reg unified cap ->
//  scratch spill, 200MB HBM/dispatch. Cap must be 256: launch_bounds(256,2).)
__global__ __launch_bounds__(256, 2) void k2_attn(
    const u16* __restrict__ qb, const u16* __restrict__ kb, const u16* __restrict__ vt,
    const float* __restrict__ vemb0, const float* __restrict__ vemb1,
    u16* __restrict__ AO)
{
    __shared__ __align__(16) u16 psa[4][32 * 72];      // per-wave P scratch
    __shared__ float Om[4][2][16][16];                 // [group][ig][row][li]
    __shared__ float lv[4][2][16];

    const int bid = blockIdx.x;
    const int rb = bid >> 4;
    const int r  = (rb < 32) ? (63 - rb) : (rb - 32);  // heavy-first complementary pairing
    const int I0 = r * 32;
    const int nJ = ((I0 + 30) >> 6) + 1;               // j <= I0+30 needed
    const int bh = bid & 15;
    const int b = bh >> 3, h = bh & 7, hkv = h >> 2;

    const int g = threadIdx.x >> 6;                    // wave = J-group 0..3
    const int lane = threadIdx.x & 63;
    const int li = lane & 15, lo4 = lane >> 4;

    u16* psw = psa[g];
    const u16* kpl = kb + ((b * HKV_ + hkv) * S_) * QB_ + (li + lo4 - 31) * QB_;
    const u16* vtp = vt + ((b * HKV_ + hkv) * VB_) * S_ + li * S_ + 8 * lo4;

    // hoist Q A-frags for both 16-row sub-tiles (rows < 0 zeroed; only I0==0 triggers)
    s16x8 qf[2][8];
    #pragma unroll
    for (int ig = 0; ig < 2; ++ig) {
        const int gr0 = I0 + 16 * ig + li - 31 + lo4;
        const u16* qp = qb + ((b * H_ + h) * S_) * QB_ + gr0 * QB_;
        #pragma unroll
        for (int kk = 0; kk < 8; ++kk) {
            s16x8 v = {0, 0, 0, 0, 0, 0, 0, 0};
            if (gr0 + 4 * kk >= 0) v = *(const s16x8*)(qp + kk * 32);
            qf[ig][kk] = v;
        }
    }

    // per-owned-row constants: i, 1/(i+1), 16/(i+1)
    int ibase[2];
    float binv[2][4], bstep[2][4];
    #pragma unroll
    for (int ig = 0; ig < 2; ++ig) {
        ibase[ig] = I0 + 16 * ig + 4 * lo4;
        #pragma unroll
        for (int reg = 0; reg < 4; ++reg) {
            float d = (float)(ibase[ig] + reg + 1);
            float rc = __builtin_amdgcn_rcpf(d);
            rc = rc * (2.f - d * rc);                  // NR: f32-exact for our range
            binv[ig][reg] = rc;
            bstep[ig][reg] = 16.f * rc;
        }
    }

    f32x4 O[2];
    O[0] = (f32x4){0.f, 0.f, 0.f, 0.f};
    O[1] = (f32x4){0.f, 0.f, 0.f, 0.f};
    float lsum[2][4] = {{0.f, 0.f, 0.f, 0.f}, {0.f, 0.f, 0.f, 0.f}};

    for (int jt = g; jt < nJ; jt += 4) {
        const int J0 = jt * 64;

        // ---- V frags (global, one b128 per K=32 slab)
        s16x8 vfr0 = *(const s16x8*)(vtp + J0);
        s16x8 vfr1 = *(const s16x8*)(vtp + J0 + 32);

        // ---- QK^T (implicit window-unfold, K=256): 20 dedup'd global loads in
        //      5 chunks of 4 (bounded live set), 64 MFMAs.
        //      frag(ns,kk) = load[4ns+kk]; chunk c covers m=4c+j -> (ns=c,kk=j)
        //      and (ns=c-1,kk=j+4).
        f32x4 sacc[2][4];
        #pragma unroll
        for (int ig = 0; ig < 2; ++ig)
            #pragma unroll
            for (int ns = 0; ns < 4; ++ns)
                sacc[ig][ns] = (f32x4){0.f, 0.f, 0.f, 0.f};

        const u16* kt = kpl + jt * 512;
        if (jt == 0) {
            #pragma unroll
            for (int c = 0; c < 5; ++c) {
                s16x8 f[4];
                #pragma unroll
                for (int j = 0; j < 4; ++j) {
                    int m = 4 * c + j;
                    s16x8 v = {0, 0, 0, 0, 0, 0, 0, 0};
                    if (li + lo4 + 4 * m >= 31) v = *(const s16x8*)(kt + 32 * m);
                    f[j] = v;
                }
                #pragma unroll
                for (int j = 0; j < 4; ++j) {
                    if (c < 4) {
                        sacc[0][c] = mfma16(qf[0][j], f[j], sacc[0][c]);
                        sacc[1][c] = mfma16(qf[1][j], f[j], sacc[1][c]);
                    }
                    if (c >= 1) {
                        sacc[0][c - 1] = mfma16(qf[0][j + 4], f[j], sacc[0][c - 1]);
                        sacc[1][c - 1] = mfma16(qf[1][j + 4], f[j], sacc[1][c - 1]);
                    }
                }
            }
        } else {
            #pragma unroll
            for (int c = 0; c < 5; ++c) {
                s16x8 f[4];
                #pragma unroll
                for (int j = 0; j < 4; ++j)
                    f[j] = *(const s16x8*)(kt + 32 * (4 * c + j));
                #pragma unroll
                for (int j = 0; j < 4; ++j) {
                    if (c < 4) {
                        sacc[0][c] = mfma16(qf[0][j], f[j], sacc[0][c]);
                        sacc[1][c] = mfma16(qf[1][j], f[j], sacc[1][c]);
                    }
                    if (c >= 1) {
                        sacc[0][c - 1] = mfma16(qf[0][j + 4], f[j], sacc[0][c - 1]);
                        sacc[1][c - 1] = mfma16(qf[1][j + 4], f[j], sacc[1][c - 1]);
                    }
                }
            }
        }

        // ---- bias + strict mask + fixed-max exp (q pre-scaled); P -> per-wave LDS
        const float jlif = (float)(J0 + li);
        #pragma unroll
        for (int ig = 0; ig < 2; ++ig) {
            const bool edgev = (J0 + 63) >= (I0 + 16 * ig);   // wave-uniform
            #pragma unroll
            for (int reg = 0; reg < 4; ++reg) {
                float bns = fmaf(jlif, binv[ig][reg], -MFIX_);
                const int irow = ibase[ig] + reg;
                float p[4];
                #pragma unroll
                for (int ns = 0; ns < 4; ++ns) {
                    float e = __expf(sacc[ig][ns][reg] + bns);
                    if (edgev)
                        e = (J0 + 16 * ns + li < irow) ? e : 0.f;
                    p[ns] = e;
                    bns += bstep[ig][reg];
                }
                lsum[ig][reg] += (p[0] + p[1]) + (p[2] + p[3]);
                #pragma unroll
                for (int ns = 0; ns < 4; ++ns)
                    psw[(ig * 16 + 4 * lo4 + reg) * 72 + 16 * ns + li] = f2bf(p[ns]);
            }
        }

        // ---- PV: P from per-wave LDS (same-wave ordering), V from global
        #pragma unroll
        for (int ig = 0; ig < 2; ++ig) {
            s16x8 pa0 = *(const s16x8*)&psw[(ig * 16 + li) * 72 + 8 * lo4];
            s16x8 pa1 = *(const s16x8*)&psw[(ig * 16 + li) * 72 + 32 + 8 * lo4];
            O[ig] = mfma16(pa0, vfr0, O[ig]);
            O[ig] = mfma16(pa1, vfr1, O[ig]);
        }
    }

    // ---- publish partials (plain-sum merge: fixed max => no rescale)
    #pragma unroll
    for (int ig = 0; ig < 2; ++ig) {
        #pragma unroll
        for (int reg = 0; reg < 4; ++reg) {
            float l = lsum[ig][reg];
            l += __shfl_xor(l, 1);
            l += __shfl_xor(l, 2);
            l += __shfl_xor(l, 4);
            l += __shfl_xor(l, 8);
            Om[g][ig][4 * lo4 + reg][li] = O[ig][reg];
            if (li == 0) lv[g][ig][4 * lo4 + reg] = l;
        }
    }
    __syncthreads();

    if (g == 0) {
        const int hc = h * VB_ + li;
        const float e0 = vemb0[hc], e1 = vemb1[hc];
        #pragma unroll
        for (int ig = 0; ig < 2; ++ig) {
            #pragma unroll
            for (int reg = 0; reg < 4; ++reg) {
                const int row = 4 * lo4 + reg;
                float Oc = (Om[0][ig][row][li] + Om[1][ig][row][li])
                         + (Om[2][ig][row][li] + Om[3][ig][row][li]);
                float lc = (lv[0][ig][row] + lv[1][ig][row])
                         + (lv[2][ig][row] + lv[3][ig][row]);
                float lr = fmaxf(lc, 1e-30f);
                float rinv = __builtin_amdgcn_rcpf(lr);
                rinv = rinv * (2.f - lr * rinv);
                float o = Oc * rinv;
                const int s = I0 + 16 * ig + row;
                AO[(b * S_ + s) * HVB_ + hc] = f2bf(e0 + o * (e1 - e0));
            }
        }
    }
}

// ------------------------------------------------- K3: AO(bf16) @ Wo^T(bf16), no LDS
// grid 1024 = 256 row-tiles x 4 col-groups; block 256 (4 waves), wave owns 2 frags
__global__ __launch_bounds__(256) void k3_out(
    const u16* __restrict__ AO, const u16* __restrict__ Wob,
    float* __restrict__ out)
{
    const int tid = threadIdx.x;
    const int r0 = (blockIdx.x >> 2) * 16;
    const int cg = blockIdx.x & 3;
    const int wv = tid >> 6, lane = tid & 63;
    const int li = lane & 15, lo4 = lane >> 4;

    const u16* arow = AO + (r0 + li) * HVB_;

    f32x4 acc[2];
    acc[0] = (f32x4){0.f, 0.f, 0.f, 0.f};
    acc[1] = (f32x4){0.f, 0.f, 0.f, 0.f};

    #pragma unroll
    for (int kc = 0; kc < 4; ++kc) {
        s16x8 a = *(const s16x8*)&arow[32 * kc + 8 * lo4];
        #pragma unroll
        for (int u = 0; u < 2; ++u) {
            int o = cg * 128 + (wv + 4 * u) * 16 + li;
            s16x8 bfr = *(const s16x8*)&Wob[o * HVB_ + 32 * kc + 8 * lo4];
            acc[u] = mfma16(a, bfr, acc[u]);
        }
    }

    #pragma unroll
    for (int u = 0; u < 2; ++u) {
        int o = cg * 128 + (wv + 4 * u) * 16 + li;
        #pragma unroll
        for (int reg = 0; reg < 4; ++reg)
            out[(r0 + 4 * lo4 + reg) * HID_ + o] = acc[u][reg];
    }
}

// ------------------------------------------------- launch
extern "C" void kernel_launch(void* const* d_in, const int* in_sizes, int n_in,
                              void* d_out, int out_size, void* d_ws, size_t ws_size,
                              hipStream_t stream)
{
    (void)in_sizes; (void)n_in; (void)out_size;
    const float* hidden = (const float*)d_in[0];
    const float* Wq = (const float*)d_in[1];
    const float* Wk = (const float*)d_in[2];
    const float* Wv = (const float*)d_in[3];
    const float* Wo = (const float*)d_in[4];
    const float* ve0 = (const float*)d_in[5];
    const float* ve1 = (const float*)d_in[6];
    float* out = (float*)d_out;

    char* base = (char*)d_ws;
    u16* qb  = (u16*)(base);                        // [B,H,S,8]      524288 B (pre-scaled 2^-4)
    u16* kb  = (u16*)(base + 524288);               // [B,HKV,S,8]    131072 B
    u16* vt  = (u16*)(base + 655360);               // [B,HKV,16,S]   262144 B (shifted, transposed)
    u16* AO  = (u16*)(base + 917504);               // [B*S,128] bf16 1048576 B
    u16* Wc  = (u16*)(base + 1966080);              // [128,512] bf16  131072 B (padded)
    u16* Wob = (u16*)(base + 2097152);              // [512,128] bf16  131072 B -> end 2228224
    if (ws_size < 2228224) return;

    hipLaunchKernelGGL(k0_convert, dim3(256), dim3(256), 0, stream,
                       Wq, Wk, Wv, Wo, Wc, Wob);
    hipLaunchKernelGGL(k1_proj, dim3(256), dim3(256), 0, stream,
                       hidden, Wc, qb, kb, vt);
    hipLaunchKernelGGL(k2_attn, dim3(1024), dim3(256), 0, stream,
                       qb, kb, vt, ve0, ve1, AO);
    hipLaunchKernelGGL(k3_out, dim3(1024), dim3(256), 0, stream,
                       AO, Wob, out);
}

// Round 10
// 62.897 us; speedup vs baseline: 2.1924x; 1.0416x over previous
//
#include <hip/hip_runtime.h>
#include <hip/hip_bf16.h>

typedef unsigned int u32;
typedef unsigned short u16;
typedef float f32x4 __attribute__((ext_vector_type(4)));
typedef short s16x8 __attribute__((ext_vector_type(8)));

#define B_   2
#define S_   2048
#define HID_ 512
#define H_   8
#define HKV_ 2
#define QB_  8
#define VB_  16
#define NQ_  64
#define HVB_ 128
#define LOG2E_ 1.4426950408889634f
#define MFIX2_ 24.525815695089866f   /* 17 * log2(e) */

__device__ __forceinline__ u16 f2bf(float f) {
    u32 b = __builtin_bit_cast(u32, f);
    b += 0x7FFFu + ((b >> 16) & 1u);
    return (u16)(b >> 16);
}
// single-instruction RNE f32->bf16 (fptrunc); bit-identical to f2bf for finite f
__device__ __forceinline__ u16 bf16u(float f) {
    return __builtin_bit_cast(u16, (__bf16)f);
}
__device__ __forceinline__ f32x4 mfma16(s16x8 a, s16x8 b, f32x4 c) {
    return __builtin_amdgcn_mfma_f32_16x16x32_bf16(a, b, c, 0, 0, 0);
}
// NaN-free by range analysis: e in [0,inf] -> rcp in [0,1] -> result in [-1,1].
__device__ __forceinline__ float fast_tanh(float x) {
    float e = exp2f(x * (2.f * LOG2E_));
    return 1.f - 2.f * __builtin_amdgcn_rcpf(e + 1.f);
}
__device__ __forceinline__ float fast_sigmoid(float x) {
    return __builtin_amdgcn_rcpf(1.f + exp2f(-LOG2E_ * x));
}

// ------------------------------------------------- K0: weights -> single bf16 planes
// Wc [128][512] row-major (rows 112..127 zero-padded); Wob [512][128] row-major.
__global__ void k0_convert(const float* __restrict__ Wq, const float* __restrict__ Wk,
                           const float* __restrict__ Wv, const float* __restrict__ Wo,
                           u16* __restrict__ Wc, u16* __restrict__ Wob) {
    int idx = blockIdx.x * 256 + threadIdx.x;          // grid 256 -> 65536 threads
    {
        int n = idx >> 9, k = idx & 511;
        float v = (n < NQ_) ? Wq[n * HID_ + k]
                : (n < NQ_ + 16) ? Wk[(n - NQ_) * HID_ + k]
                : (n < 112) ? Wv[(n - NQ_ - 16) * HID_ + k] : 0.f;
        Wc[idx] = f2bf(v);                             // idx == n*512 + k
    }
    Wob[idx] = f2bf(Wo[idx]);                          // 512*128 == 65536
}

// ------------------------------------------------- K1: projections (single bf16, no LDS)
// grid 256 (16 rows), block 256 (4 waves); wave wv owns n-frags {wv, wv+4}.
// q is PRE-SCALED by log2(e)/16 so k2's scores are directly in exp2 domain.
__global__ __launch_bounds__(256) void k1_proj(
    const float* __restrict__ hidden, const u16* __restrict__ Wc,
    u16* __restrict__ qb, u16* __restrict__ kb, u16* __restrict__ vt)
{
    const int tid = threadIdx.x;
    const int r0 = blockIdx.x * 16;
    const int wv = tid >> 6, lane = tid & 63;
    const int li = lane & 15, lo4 = lane >> 4;

    const float* hrow = hidden + (r0 + li) * HID_;

    f32x4 acc[2];
    acc[0] = (f32x4){0.f, 0.f, 0.f, 0.f};
    acc[1] = (f32x4){0.f, 0.f, 0.f, 0.f};

    #pragma unroll
    for (int kc = 0; kc < 16; ++kc) {
        f32x4 x0 = *(const f32x4*)&hrow[32 * kc + 8 * lo4];
        f32x4 x1 = *(const f32x4*)&hrow[32 * kc + 8 * lo4 + 4];
        s16x8 a = { (short)f2bf(x0[0]), (short)f2bf(x0[1]), (short)f2bf(x0[2]), (short)f2bf(x0[3]),
                    (short)f2bf(x1[0]), (short)f2bf(x1[1]), (short)f2bf(x1[2]), (short)f2bf(x1[3]) };
        #pragma unroll
        for (int u = 0; u < 2; ++u) {
            int n = (wv + 4 * u) * 16 + li;
            s16x8 bfr = *(const s16x8*)&Wc[n * HID_ + 32 * kc + 8 * lo4];
            acc[u] = mfma16(a, bfr, acc[u]);
        }
    }

    #pragma unroll
    for (int u = 0; u < 2; ++u) {
        int n = (wv + 4 * u) * 16 + li;
        if (n < 112) {
            #pragma unroll
            for (int reg = 0; reg < 4; ++reg) {
                int gs = r0 + 4 * lo4 + reg;
                int b = gs >> 11, s = gs & 2047;
                float pre = acc[u][reg];
                if (n < NQ_) {
                    int h = n >> 3, bit = n & 7;
                    qb[(((b * H_ + h) * S_) + s) * QB_ + bit] =
                        f2bf(fast_tanh(pre) * (0.0625f * LOG2E_));
                } else if (n < NQ_ + 16) {
                    int nk = n - NQ_;
                    kb[(((b * HKV_ + (nk >> 3)) * S_) + s) * QB_ + (nk & 7)] = f2bf(fast_tanh(pre));
                } else {
                    int nv = n - NQ_ - 16;
                    int hv = nv >> 4, vb = nv & 15;
                    u16 sig = f2bf(fast_sigmoid(pre));
                    if (s > 0)
                        vt[((b * HKV_ + hv) * VB_ + vb) * S_ + (s - 1)] = sig;   // suffix shift
                    if (s == S_ - 1)
                        vt[((b * HKV_ + hv) * VB_ + vb) * S_ + (S_ - 1)] = 0;
                }
            }
        }
    }
}

// ------------------------------------------------- K2: fused windowed attention
// grid 1024 = 64 row-blocks(32 i) x 16 bh; block 256 = 4 waves = 4 J-groups.
// Barrier-free main loop. Cross-tile prefetch: flat ld[20] reloaded for tile
// jt+4 right after QK consumes it (latency hides under softmax+PV); V issued
// at loop top (hides under QK). launch_bounds(256,2): 256-reg cap, no spill
// (r8 lesson: 128-reg cap spilled ld[] to scratch -> 200MB HBM/dispatch).
__global__ __launch_bounds__(256, 2) void k2_attn(
    const u16* __restrict__ qb, const u16* __restrict__ kb, const u16* __restrict__ vt,
    const float* __restrict__ vemb0, const float* __restrict__ vemb1,
    u16* __restrict__ AO)
{
    __shared__ __align__(16) u16 psa[4][32 * 72];      // per-wave P scratch
    __shared__ float Om[4][2][16][16];                 // [group][ig][row][li]
    __shared__ float lv[4][2][16];

    const int bid = blockIdx.x;
    const int rb = bid >> 4;
    const int r  = (rb < 32) ? (63 - rb) : (rb - 32);  // heavy-first complementary pairing
    const int I0 = r * 32;
    const int nJ = ((I0 + 30) >> 6) + 1;               // j <= I0+30 needed
    const int bh = bid & 15;
    const int b = bh >> 3, h = bh & 7, hkv = h >> 2;

    const int g = threadIdx.x >> 6;                    // wave = J-group 0..3
    const int lane = threadIdx.x & 63;
    const int li = lane & 15, lo4 = lane >> 4;

    u16* psw = psa[g];
    const u16* kpl = kb + ((b * HKV_ + hkv) * S_) * QB_ + (li + lo4 - 31) * QB_;
    const u16* vtp = vt + ((b * HKV_ + hkv) * VB_) * S_ + li * S_ + 8 * lo4;

    // hoist Q A-frags for both 16-row sub-tiles (rows < 0 zeroed; only I0==0 triggers)
    s16x8 qf[2][8];
    #pragma unroll
    for (int ig = 0; ig < 2; ++ig) {
        const int gr0 = I0 + 16 * ig + li - 31 + lo4;
        const u16* qp = qb + ((b * H_ + h) * S_) * QB_ + gr0 * QB_;
        #pragma unroll
        for (int kk = 0; kk < 8; ++kk) {
            s16x8 v = {0, 0, 0, 0, 0, 0, 0, 0};
            if (gr0 + 4 * kk >= 0) v = *(const s16x8*)(qp + kk * 32);
            qf[ig][kk] = v;
        }
    }

    // per-owned-row constants: i, log2e/(i+1)
    int ibase[2];
    float binv[2][4];
    #pragma unroll
    for (int ig = 0; ig < 2; ++ig) {
        ibase[ig] = I0 + 16 * ig + 4 * lo4;
        #pragma unroll
        for (int reg = 0; reg < 4; ++reg) {
            float d = (float)(ibase[ig] + reg + 1);
            float rc = __builtin_amdgcn_rcpf(d);
            rc = rc * (2.f - d * rc);                  // NR: f32-exact for our range
            binv[ig][reg] = rc * LOG2E_;
        }
    }

    f32x4 O[2];
    O[0] = (f32x4){0.f, 0.f, 0.f, 0.f};
    O[1] = (f32x4){0.f, 0.f, 0.f, 0.f};
    float lsum[2][4] = {{0.f, 0.f, 0.f, 0.f}, {0.f, 0.f, 0.f, 0.f}};

    // prologue: K loads for first tile (jt = g). Waves with g >= nJ read valid
    // memory (rows < 256 < S) and never use the values.
    s16x8 ld[20];
    {
        const u16* kt = kpl + g * 512;
        if (g == 0) {
            #pragma unroll
            for (int m = 0; m < 20; ++m) {
                s16x8 v = {0, 0, 0, 0, 0, 0, 0, 0};
                if (li + lo4 + 4 * m >= 31) v = *(const s16x8*)(kt + 32 * m);
                ld[m] = v;
            }
        } else {
            #pragma unroll
            for (int m = 0; m < 20; ++m)
                ld[m] = *(const s16x8*)(kt + 32 * m);
        }
    }

    for (int jt = g; jt < nJ; jt += 4) {
        const int J0 = jt * 64;

        // ---- V frags for THIS tile: issue early, consumed after softmax
        s16x8 vfr0 = *(const s16x8*)(vtp + J0);
        s16x8 vfr1 = *(const s16x8*)(vtp + J0 + 32);

        // ---- QK^T (implicit window-unfold, K=256): 64 MFMAs off prefetched ld
        //      frag(ns,kk) = ld[4ns+kk]
        f32x4 sacc[2][4];
        #pragma unroll
        for (int ig = 0; ig < 2; ++ig)
            #pragma unroll
            for (int ns = 0; ns < 4; ++ns)
                sacc[ig][ns] = (f32x4){0.f, 0.f, 0.f, 0.f};
        #pragma unroll
        for (int m = 0; m < 20; ++m) {
            s16x8 f = ld[m];
            {
                int kk = m & 3, ns = m >> 2;
                if (ns < 4) {
                    sacc[0][ns] = mfma16(qf[0][kk], f, sacc[0][ns]);
                    sacc[1][ns] = mfma16(qf[1][kk], f, sacc[1][ns]);
                }
            }
            {
                int kk = (m & 3) + 4, ns = (m >> 2) - 1;
                if (ns >= 0) {
                    sacc[0][ns] = mfma16(qf[0][kk], f, sacc[0][ns]);
                    sacc[1][ns] = mfma16(qf[1][kk], f, sacc[1][ns]);
                }
            }
        }

        // ---- prefetch NEXT tile's K (in flight during softmax+PV)
        if (jt + 4 < nJ) {
            const u16* kt = kpl + (jt + 4) * 512;
            #pragma unroll
            for (int m = 0; m < 20; ++m)
                ld[m] = *(const s16x8*)(kt + 32 * m);
        }

        // ---- bias + strict mask + fixed-max exp2 (q pre-scaled by log2e/16)
        const float jlif = (float)(J0 + li);
        #pragma unroll
        for (int ig = 0; ig < 2; ++ig) {
            const bool edgev = (J0 + 63) >= (I0 + 16 * ig);   // wave-uniform
            #pragma unroll
            for (int reg = 0; reg < 4; ++reg) {
                const int irow = ibase[ig] + reg;
                const float bi = binv[ig][reg];
                float p[4];
                #pragma unroll
                for (int ns = 0; ns < 4; ++ns) {
                    float bns = fmaf(jlif + (float)(16 * ns), bi, -MFIX2_);
                    float e = exp2f(sacc[ig][ns][reg] + bns);
                    if (edgev)
                        e = (J0 + 16 * ns + li < irow) ? e : 0.f;
                    p[ns] = e;
                }
                lsum[ig][reg] += (p[0] + p[1]) + (p[2] + p[3]);
                #pragma unroll
                for (int ns = 0; ns < 4; ++ns)
                    psw[(ig * 16 + 4 * lo4 + reg) * 72 + 16 * ns + li] = bf16u(p[ns]);
            }
        }

        // ---- PV: P from per-wave LDS (same-wave ordering), V from regs
        #pragma unroll
        for (int ig = 0; ig < 2; ++ig) {
            s16x8 pa0 = *(const s16x8*)&psw[(ig * 16 + li) * 72 + 8 * lo4];
            s16x8 pa1 = *(const s16x8*)&psw[(ig * 16 + li) * 72 + 32 + 8 * lo4];
            O[ig] = mfma16(pa0, vfr0, O[ig]);
            O[ig] = mfma16(pa1, vfr1, O[ig]);
        }
    }

    // ---- publish partials (plain-sum merge: fixed max => no rescale)
    #pragma unroll
    for (int ig = 0; ig < 2; ++ig) {
        #pragma unroll
        for (int reg = 0; reg < 4; ++reg) {
            float l = lsum[ig][reg];
            l += __shfl_xor(l, 1);
            l += __shfl_xor(l, 2);
            l += __shfl_xor(l, 4);
            l += __shfl_xor(l, 8);
            Om[g][ig][4 * lo4 + reg][li] = O[ig][reg];
            if (li == 0) lv[g][ig][4 * lo4 + reg] = l;
        }
    }
    __syncthreads();

    if (g == 0) {
        const int hc = h * VB_ + li;
        const float e0 = vemb0[hc], e1 = vemb1[hc];
        #pragma unroll
        for (int ig = 0; ig < 2; ++ig) {
            #pragma unroll
            for (int reg = 0; reg < 4; ++reg) {
                const int row = 4 * lo4 + reg;
                float Oc = (Om[0][ig][row][li] + Om[1][ig][row][li])
                         + (Om[2][ig][row][li] + Om[3][ig][row][li]);
                float lc = (lv[0][ig][row] + lv[1][ig][row])
                         + (lv[2][ig][row] + lv[3][ig][row]);
                float lr = fmaxf(lc, 1e-30f);
                float rinv = __builtin_amdgcn_rcpf(lr);
                rinv = rinv * (2.f - lr * rinv);
                float o = Oc * rinv;
                const int s = I0 + 16 * ig + row;
                AO[(b * S_ + s) * HVB_ + hc] = f2bf(e0 + o * (e1 - e0));
            }
        }
    }
}

// ------------------------------------------------- K3: AO(bf16) @ Wo^T(bf16), no LDS
// grid 1024 = 256 row-tiles x 4 col-groups; block 256 (4 waves), wave owns 2 frags
__global__ __launch_bounds__(256) void k3_out(
    const u16* __restrict__ AO, const u16* __restrict__ Wob,
    float* __restrict__ out)
{
    const int tid = threadIdx.x;
    const int r0 = (blockIdx.x >> 2) * 16;
    const int cg = blockIdx.x & 3;
    const int wv = tid >> 6, lane = tid & 63;
    const int li = lane & 15, lo4 = lane >> 4;

    const u16* arow = AO + (r0 + li) * HVB_;

    f32x4 acc[2];
    acc[0] = (f32x4){0.f, 0.f, 0.f, 0.f};
    acc[1] = (f32x4){0.f, 0.f, 0.f, 0.f};

    #pragma unroll
    for (int kc = 0; kc < 4; ++kc) {
        s16x8 a = *(const s16x8*)&arow[32 * kc + 8 * lo4];
        #pragma unroll
        for (int u = 0; u < 2; ++u) {
            int o = cg * 128 + (wv + 4 * u) * 16 + li;
            s16x8 bfr = *(const s16x8*)&Wob[o * HVB_ + 32 * kc + 8 * lo4];
            acc[u] = mfma16(a, bfr, acc[u]);
        }
    }

    #pragma unroll
    for (int u = 0; u < 2; ++u) {
        int o = cg * 128 + (wv + 4 * u) * 16 + li;
        #pragma unroll
        for (int reg = 0; reg < 4; ++reg)
            out[(r0 + 4 * lo4 + reg) * HID_ + o] = acc[u][reg];
    }
}

// ------------------------------------------------- launch
extern "C" void kernel_launch(void* const* d_in, const int* in_sizes, int n_in,
                              void* d_out, int out_size, void* d_ws, size_t ws_size,
                              hipStream_t stream)
{
    (void)in_sizes; (void)n_in; (void)out_size;
    const float* hidden = (const float*)d_in[0];
    const float* Wq = (const float*)d_in[1];
    const float* Wk = (const float*)d_in[2];
    const float* Wv = (const float*)d_in[3];
    const float* Wo = (const float*)d_in[4];
    const float* ve0 = (const float*)d_in[5];
    const float* ve1 = (const float*)d_in[6];
    float* out = (float*)d_out;

    char* base = (char*)d_ws;
    u16* qb  = (u16*)(base);                        // [B,H,S,8]      524288 B (pre-scaled log2e/16)
    u16* kb  = (u16*)(base + 524288);               // [B,HKV,S,8]    131072 B
    u16* vt  = (u16*)(base + 655360);               // [B,HKV,16,S]   262144 B (shifted, transposed)
    u16* AO  = (u16*)(base + 917504);               // [B*S,128] bf16 1048576 B
    u16* Wc  = (u16*)(base + 1966080);              // [128,512] bf16  131072 B (padded)
    u16* Wob = (u16*)(base + 2097152);              // [512,128] bf16  131072 B -> end 2228224
    if (ws_size < 2228224) return;

    hipLaunchKernelGGL(k0_convert, dim3(256), dim3(256), 0, stream,
                       Wq, Wk, Wv, Wo, Wc, Wob);
    hipLaunchKernelGGL(k1_proj, dim3(256), dim3(256), 0, stream,
                       hidden, Wc, qb, kb, vt);
    hipLaunchKernelGGL(k2_attn, dim3(1024), dim3(256), 0, stream,
                       qb, kb, vt, ve0, ve1, AO);
    hipLaunchKernelGGL(k3_out, dim3(1024), dim3(256), 0, stream,
                       AO, Wob, out);
}